// Round 8
// baseline (9761.012 us; speedup 1.0000x reference)
//
#include <hip/hip_runtime.h>
#include <math.h>

#define TSTEPS 100
#define BB 256
#define FF 1024
#define NIN 784
#define NW 13           // 13*64 = 832 >= 784 bits per input row
#define CAPA 192        // max pre-spikes per (t,b)
#define CAPB 128        // max pre-spikes per (t,i)
#define NBLK 2048       // 8 blocks/CU x 256 CU, co-resident by capacity
#define TPB 128

typedef unsigned long long u64;

// device-coherent atomic helpers (relaxed, agent scope — proven in r6)
__device__ __forceinline__ unsigned at_add(unsigned* p, unsigned v) {
    return __hip_atomic_fetch_add(p, v, __ATOMIC_RELAXED, __HIP_MEMORY_SCOPE_AGENT);
}
__device__ __forceinline__ unsigned at_ld(unsigned* p) {
    return __hip_atomic_load(p, __ATOMIC_RELAXED, __HIP_MEMORY_SCOPE_AGENT);
}
__device__ __forceinline__ void at_st(unsigned* p, unsigned v) {
    __hip_atomic_store(p, v, __ATOMIC_RELAXED, __HIP_MEMORY_SCOPE_AGENT);
}
__device__ __forceinline__ u64 at_ld64(u64* p) {
    return __hip_atomic_load(p, __ATOMIC_RELAXED, __HIP_MEMORY_SCOPE_AGENT);
}
__device__ __forceinline__ void at_st64(u64* p, u64 v) {
    __hip_atomic_store(p, v, __ATOMIC_RELAXED, __HIP_MEMORY_SCOPE_AGENT);
}

// ---------- one-time init: zero state, transpose W ----------
__global__ __launch_bounds__(256) void k_init(
    const float* __restrict__ W, float* __restrict__ wT,
    float* __restrict__ apre_g, float* __restrict__ mem, float* __restrict__ apost,
    float* __restrict__ out, u64* __restrict__ spkbits, u64* __restrict__ spkT,
    unsigned* __restrict__ bar)
{
    int idx = blockIdx.x * 256 + threadIdx.x;          // covers NIN*FF = 802816
    {
        int f = idx & (FF - 1);
        int i = idx >> 10;
        wT[idx] = W[f * NIN + i];                      // wT[i][f] = W[f][i]
    }
    apre_g[idx] = 0.f;                                 // 8 copies = 2*802816 elems
    apre_g[idx + NIN * FF] = 0.f;
    if (idx < BB * FF) { mem[idx] = 0.f; apost[idx] = 0.f; out[idx] = 0.f; }
    if (idx < BB * (FF / 64)) spkbits[idx] = 0ull;
    if (idx < 2 * FF * 4) spkT[idx] = 0ull;
    if (idx < 1024) bar[idx] = 0u;
}

// ---------- Poisson encode (pure f32): p = image*0.2f; noise < p ----------
__global__ __launch_bounds__(256) void k_encode(
    const float* __restrict__ image, const float* __restrict__ noise,
    u64* __restrict__ prebits)
{
    int tid = blockIdx.x * 256 + threadIdx.x;
    int lane = threadIdx.x & 63;
    int word = tid >> 6;           // (t*BB + b)*NW + wd
    int wd = word % NW;
    int tb = word / NW;
    int b = tb & (BB - 1);
    int i = (wd << 6) + lane;
    bool s = false;
    if (i < NIN) {
        float pf = __fmul_rn(image[b * NIN + i], 0.2f);
        s = (noise[(size_t)tb * NIN + i] < pf);
    }
    u64 m = __ballot(s);
    if (lane == 0) prebits[word] = m;
}

// ---------- transposed prebits: prebitsT[t][i][wb] (bit = batch b) ----------
__global__ __launch_bounds__(256) void k_encode_t(
    const u64* __restrict__ prebits, u64* __restrict__ prebitsT)
{
    int tid = blockIdx.x * 256 + threadIdx.x;
    int b = tid & (BB - 1);
    int ti = tid >> 8;             // t*NIN + i
    int i = ti % NIN;
    int t = ti / NIN;
    u64 w = prebits[((size_t)t * BB + b) * NW + (i >> 6)];
    bool s = (w >> (i & 63)) & 1ull;
    u64 m = __ballot(s);
    if ((threadIdx.x & 63) == 0)
        prebitsT[(size_t)ti * 4 + ((threadIdx.x >> 6) & 3)] = m;
}

// ---------- index lists per (t,b): ascending i, KC=384 chunk marks ----------
__global__ __launch_bounds__(256) void k_lists(
    const u64* __restrict__ prebits, unsigned short* __restrict__ idxA,
    unsigned short* __restrict__ cntA)
{
    int tb = blockIdx.x * 256 + threadIdx.x;
    const u64* pb = prebits + (size_t)tb * NW;
    unsigned short* ia = idxA + (size_t)tb * CAPA;
    int n = 0, c1 = 0, c2 = 0;
    for (int wd = 0; wd < NW; ++wd) {
        u64 m = pb[wd];
        int boff = wd << 6;
        while (m) {
            int j = __builtin_ctzll(m); m &= m - 1;
            if (n < CAPA) ia[n] = (unsigned short)(boff + j);
            ++n;
        }
        if (wd == 5)  c1 = n;     // i < 384 boundary
        if (wd == 11) c2 = n;     // i < 768 boundary
    }
    if (n > CAPA) n = CAPA;
    if (c2 > n) c2 = n;
    if (c1 > c2) c1 = c2;
    cntA[tb * 4 + 0] = (unsigned short)c1;
    cntA[tb * 4 + 1] = (unsigned short)c2;
    cntA[tb * 4 + 2] = (unsigned short)n;
}

// ---------- b-lists per (t,i): ascending b ----------
__global__ __launch_bounds__(256) void k_listsT(
    const u64* __restrict__ prebitsT, unsigned char* __restrict__ idxB,
    unsigned short* __restrict__ cntB)
{
    int ti = blockIdx.x * 256 + threadIdx.x;
    if (ti >= TSTEPS * NIN) return;
    const u64* pt = prebitsT + (size_t)ti * 4;
    unsigned char* ib = idxB + (size_t)ti * CAPB;
    int n = 0;
    for (int wb = 0; wb < 4; ++wb) {
        u64 m = pt[wb];
        int boff = wb << 6;
        while (m) {
            int j = __builtin_ctzll(m); m &= m - 1;
            if (n < CAPB) ib[n] = (unsigned char)(boff + j);
            ++n;
        }
    }
    cntB[ti] = (unsigned short)(n > CAPB ? CAPB : n);
}

// ---------- persistent kernel: XCD-self-organizing, XCD-local barriers ----------
// Coherence model: stores are write-through to the XCD's own L2; barrier does
// NO device fence (no L2 flush); stale L1 killed by `buffer_inv sc0` (L1-only).
// Cross-block-visible masks/counters use device-coherent atomics end-to-end.
__global__ __launch_bounds__(TPB, 4) void k_run(
    float* __restrict__ wT, float* __restrict__ apre_g, float* __restrict__ apost,
    float* __restrict__ mem,
    const u64* __restrict__ prebits,
    const unsigned short* __restrict__ idxA, const unsigned short* __restrict__ cntA,
    const unsigned char* __restrict__ idxB, const unsigned short* __restrict__ cntB,
    u64* __restrict__ spkbits, u64* __restrict__ spkT,
    float* __restrict__ out, unsigned* __restrict__ bar,
    float dmem, float dpre, float dpost, float lrp, float lrm)
{
    __shared__ int sh[4];          // xcd, rank, nx, nsl
    __shared__ int shs[8];         // slice list for this group
    int tix = threadIdx.x;

    if (tix == 0) {
        unsigned xcd;
        asm volatile("s_getreg_b32 %0, hwreg(HW_REG_XCC_ID)" : "=s"(xcd));
        xcd &= 7u;
        unsigned rank = at_add(bar + xcd * 16, 1u);
        asm volatile("s_waitcnt vmcnt(0)" ::: "memory");   // rank-add visible first
        unsigned a = at_add(bar + 128, 1u);
        if (a == NBLK - 1u) at_st(bar + 136, 1u);
        unsigned spins = 0;
        while (at_ld(bar + 136) == 0u) {
            if (++spins > (1u << 24)) break;               // fail fast, not hang
            __builtin_amdgcn_s_sleep(2);
        }
        int cnts[8]; int Kn = 0, gidx = 0;
        for (int x = 0; x < 8; ++x) cnts[x] = (int)at_ld(bar + x * 16);
        for (int x = 0; x < 8; ++x)
            if (cnts[x] > 0) { if (x == (int)xcd) gidx = Kn; ++Kn; }
        int ns = 0;
        for (int s = 0; s < 8; ++s) if ((s % Kn) == gidx) shs[ns++] = s;
        sh[0] = (int)xcd; sh[1] = (int)rank; sh[2] = cnts[xcd]; sh[3] = ns;
    }
    __syncthreads();
    const int xcd = sh[0], rank = sh[1], nx = sh[2], nsl = sh[3];

    unsigned ep = 1;
    auto gbar = [&]() {
        __syncthreads();                                   // drains vmcnt per wave
        if (tix == 0) {
            asm volatile("s_waitcnt vmcnt(0)" ::: "memory");
            int nsub = nx < 8 ? nx : 8;
            int sub = rank % nsub;
            unsigned need = (unsigned)((nx - sub + nsub - 1) / nsub);
            unsigned v = at_add(bar + 256 + (xcd * 8 + sub) * 8, 1u);
            if (v == need * ep - 1u) {
                unsigned r = at_add(bar + 768 + xcd * 16, 1u);
                if (r == (unsigned)nsub * ep - 1u)
                    at_st(bar + 896 + xcd * 16, ep);
            }
            unsigned spins = 0;
            while (at_ld(bar + 896 + xcd * 16) < ep) {
                if (++spins > (1u << 24)) break;
                __builtin_amdgcn_s_sleep(1);
            }
        }
        __syncthreads();
        asm volatile("buffer_inv sc0" ::: "memory");       // L1-only invalidate
        ++ep;
    };

    for (int t = 0; t < TSTEPS; ++t) {
        u64* cur = spkT + (size_t)(t & 1) * (FF * 4);
        u64* nxt = spkT + (size_t)((t + 1) & 1) * (FF * 4);

        // ===== phase A: units (slice, b) =====
        for (int u = rank; u < (nsl << 8); u += nx) {
            int sl = u >> 8, b = u & 255;
            int slice = shs[sl];
            int f = (slice << 7) + tix;
            int tid = (b << 10) + f;

            // apost = f32(f32(apost*decay) + spk_{t-1})
            u64 pw_ = spkbits[(b << 4) + (f >> 6)];
            float apo = __fadd_rn(__fmul_rn(apost[tid], dpost),
                                  (float)((pw_ >> (f & 63)) & 1ull));
            apost[tid] = apo;

            // I = ((chunk0 + chunk1) + chunk2), sequential f32 folds, ascending i
            const unsigned short* ia = idxA + (size_t)(t * BB + b) * CAPA;
            const unsigned short* ca = cntA + (size_t)(t * BB + b) * 4;
            int c1 = ca[0], c2 = ca[1], c3 = ca[2];
            float I = 0.f; int k = 0;
            { float c = 0.f;
              #pragma unroll 4
              for (; k < c1; ++k) c = __fadd_rn(c, wT[((int)ia[k] << 10) + f]);
              I = __fadd_rn(I, c); }
            { float c = 0.f;
              #pragma unroll 4
              for (; k < c2; ++k) c = __fadd_rn(c, wT[((int)ia[k] << 10) + f]);
              I = __fadd_rn(I, c); }
            { float c = 0.f;
              #pragma unroll 4
              for (; k < c3; ++k) c = __fadd_rn(c, wT[((int)ia[k] << 10) + f]);
              I = __fadd_rn(I, c); }

            float mm = __fadd_rn(__fmul_rn(mem[tid], dmem), I);
            bool spk = (mm >= 16.0f);
            mem[tid] = spk ? 0.f : mm;
            float cv = out[tid];
            if (spk) {
                cv += 1.f;
                atomicOr(&cur[(f << 2) | (b >> 6)], 1ull << (b & 63));
            }
            out[tid] = cv;
            u64 bal = __ballot(spk);
            if ((tix & 63) == 0) spkbits[(b << 4) + (f >> 6)] = bal;

            if (u < 256) {   // first slice also owns apre row b (slice-independent)
                float* ap = apre_g + (size_t)xcd * (BB * NIN) + (size_t)b * NIN;
                const u64* pbr = prebits + ((size_t)t * BB + b) * NW;
                for (int e = tix; e < NIN; e += TPB) {
                    u64 w_ = pbr[e >> 6];
                    float pr = (float)((w_ >> (e & 63)) & 1ull);
                    ap[e] = __fadd_rn(__fmul_rn(ap[e], dpre), pr);
                }
            }
        }
        // zero next-parity spike masks for my slices (atomic domain)
        for (int w = rank * TPB + tix; w < (nsl << 9); w += nx * TPB) {
            int sl = w >> 9, off = w & 511;
            at_st64(&nxt[(shs[sl] << 9) + off], 0ull);
        }

        if (t == TSTEPS - 1) break;
        gbar();

        // ===== phase B: units (slice, i) =====
        for (int u = rank; u < nsl * NIN; u += nx) {
            int sl = u / NIN, i = u - sl * NIN;
            int slice = shs[sl];
            int f = (slice << 7) + tix;

            // Sm = fold_{b' in pre(i)} apost[b',f], ascending b'
            const unsigned char* ib = idxB + (size_t)(t * NIN + i) * CAPB;
            int cb = cntB[t * NIN + i];
            float Sm = 0.f;
            #pragma unroll 4
            for (int k2 = 0; k2 < cb; ++k2)
                Sm = __fadd_rn(Sm, apost[((int)ib[k2] << 10) + f]);

            // Sp = fold_{b' in spk(f)} apre[b',i], ascending b'
            u64 m0 = at_ld64(&cur[(f << 2) | 0]);
            u64 m1 = at_ld64(&cur[(f << 2) | 1]);
            u64 m2 = at_ld64(&cur[(f << 2) | 2]);
            u64 m3 = at_ld64(&cur[(f << 2) | 3]);
            const float* ar = apre_g + (size_t)xcd * (BB * NIN);
            float Sp = 0.f;
            u64 m;
            m = m0; while (m) { int j = __builtin_ctzll(m); m &= m - 1;
                                Sp = __fadd_rn(Sp, ar[(size_t)j * NIN + i]); }
            m = m1; while (m) { int j = __builtin_ctzll(m); m &= m - 1;
                                Sp = __fadd_rn(Sp, ar[(size_t)(64 + j) * NIN + i]); }
            m = m2; while (m) { int j = __builtin_ctzll(m); m &= m - 1;
                                Sp = __fadd_rn(Sp, ar[(size_t)(128 + j) * NIN + i]); }
            m = m3; while (m) { int j = __builtin_ctzll(m); m &= m - 1;
                                Sp = __fadd_rn(Sp, ar[(size_t)(192 + j) * NIN + i]); }

            int wi = (i << 10) + f;
            float w = wT[wi];
            w = __fadd_rn(w, __fmul_rn(lrp, Sp));
            w = __fsub_rn(w, __fmul_rn(lrm, Sm));
            w = fminf(fmaxf(w, 0.f), 1.f);
            wT[wi] = w;
        }
        gbar();
    }
}

extern "C" void kernel_launch(void* const* d_in, const int* in_sizes, int n_in,
                              void* d_out, int out_size, void* d_ws, size_t ws_size,
                              hipStream_t stream)
{
    const float* image = (const float*)d_in[0];
    const float* W     = (const float*)d_in[1];
    const float* noise = (const float*)d_in[2];
    float* out = (float*)d_out;

    char* p = (char*)d_ws;
    float* wT      = (float*)p; p += (size_t)NIN * FF * 4;              // 3.2 MB
    float* apre_g  = (float*)p; p += (size_t)8 * BB * NIN * 4;          // 6.4 MB
    float* apost   = (float*)p; p += (size_t)BB * FF * 4;               // 1 MB
    float* mem     = (float*)p; p += (size_t)BB * FF * 4;               // 1 MB
    u64* prebits   = (u64*)p;   p += (size_t)TSTEPS * BB * NW * 8;      // 2.66 MB
    u64* prebitsT  = (u64*)p;   p += (size_t)TSTEPS * NIN * 4 * 8;      // 2.51 MB
    u64* spkbits   = (u64*)p;   p += (size_t)BB * (FF / 64) * 8;        // 32 KB
    u64* spkT      = (u64*)p;   p += (size_t)2 * FF * 4 * 8;            // 64 KB
    unsigned short* idxA = (unsigned short*)p; p += (size_t)TSTEPS * BB * CAPA * 2;
    unsigned short* cntA = (unsigned short*)p; p += (size_t)TSTEPS * BB * 4 * 2;
    unsigned char*  idxB = (unsigned char*)p;  p += (size_t)TSTEPS * NIN * CAPB;
    unsigned short* cntB = (unsigned short*)p; p += (size_t)TSTEPS * NIN * 2;
    unsigned* bar        = (unsigned*)p;       p += 1024 * 4;

    float dmem = (float)exp(-1.0 / 20.0);   // np.float32(np.exp(-0.05))
    float dpre = dmem, dpost = dmem;
    float lrp = (float)(0.01 / 256.0);
    float lrm = (float)(0.012 / 256.0);

    k_init<<<(NIN * FF) / 256, 256, 0, stream>>>(
        W, wT, apre_g, mem, apost, out, spkbits, spkT, bar);
    k_encode<<<(TSTEPS * BB * NW * 64) / 256, 256, 0, stream>>>(image, noise, prebits);
    k_encode_t<<<(TSTEPS * NIN * BB) / 256, 256, 0, stream>>>(prebits, prebitsT);
    k_lists<<<(TSTEPS * BB) / 256, 256, 0, stream>>>(prebits, idxA, cntA);
    k_listsT<<<(TSTEPS * NIN + 255) / 256, 256, 0, stream>>>(prebitsT, idxB, cntB);

    k_run<<<NBLK, TPB, 0, stream>>>(
        wT, apre_g, apost, mem, prebits, idxA, cntA, idxB, cntB,
        spkbits, spkT, out, bar, dmem, dpre, dpost, lrp, lrm);
}

// Round 9
// 8377.576 us; speedup vs baseline: 1.1651x; 1.1651x over previous
//
#include <hip/hip_runtime.h>
#include <math.h>

#define TSTEPS 100
#define BB 256
#define FF 1024
#define NIN 784
#define NW 13           // 13*64 = 832 >= 784 bits per input row

typedef unsigned long long u64;

__device__ __forceinline__ unsigned at_add(unsigned* p, unsigned v) {
    return __hip_atomic_fetch_add(p, v, __ATOMIC_RELAXED, __HIP_MEMORY_SCOPE_AGENT);
}

// ---------- Poisson encode (pure f32): p = image*0.2f; noise < p ----------
__global__ __launch_bounds__(256) void k_encode(
    const float* __restrict__ image, const float* __restrict__ noise,
    u64* __restrict__ prebits)
{
    int tid = blockIdx.x * 256 + threadIdx.x;
    int lane = threadIdx.x & 63;
    int word = tid >> 6;           // (t*BB + b)*NW + wd
    int wd = word % NW;
    int tb = word / NW;
    int b = tb & (BB - 1);
    int i = (wd << 6) + lane;
    bool s = false;
    if (i < NIN) {
        float pf = __fmul_rn(image[b * NIN + i], 0.2f);   // single f32 rounding
        s = (noise[(size_t)tb * NIN + i] < pf);           // f32 compare
    }
    u64 m = __ballot(s);
    if (lane == 0) prebits[word] = m;
}

// ---------- transposed prebits: prebitsT[t][i][wb] (bit = batch b) ----------
__global__ __launch_bounds__(256) void k_encode_t(
    const u64* __restrict__ prebits, u64* __restrict__ prebitsT)
{
    int tid = blockIdx.x * 256 + threadIdx.x;
    int b = tid & (BB - 1);
    int ti = tid >> 8;             // t*NIN + i
    int i = ti % NIN;
    int t = ti / NIN;
    u64 w = prebits[((size_t)t * BB + b) * NW + (i >> 6)];
    bool s = (w >> (i & 63)) & 1ull;
    u64 m = __ballot(s);
    if ((threadIdx.x & 63) == 0)
        prebitsT[(size_t)ti * 4 + ((threadIdx.x >> 6) & 3)] = m;
}

// ---------- precompute apre_all[t][b][i] (input-only recurrence, f32-exact) ----------
__global__ __launch_bounds__(256) void k_apre(
    const u64* __restrict__ prebits, float* __restrict__ apre_all, float dpre,
    unsigned* __restrict__ bar)
{
    int e = blockIdx.x * 256 + threadIdx.x;    // < BB*NIN = 200704
    if (e < 64) bar[e] = 0u;                   // zero XCD rank counters each call
    int b = e / NIN, i = e - b * NIN;
    float v = 0.f;
    for (int t = 0; t < TSTEPS; ++t) {
        u64 w = prebits[((size_t)t * BB + b) * NW + (i >> 6)];
        float pr = (float)((w >> (i & 63)) & 1ull);
        v = __fadd_rn(__fmul_rn(v, dpre), pr);            // apre = f32(apre*d + pre)
        apre_all[(size_t)t * (BB * NIN) + e] = v;         // coalesced store
    }
}

// ---------- the whole simulation: 1024 independent per-f-column blocks ----------
// Block f owns w[:,f] (LDS), apost[:,f] (LDS), mem/cnt (regs). No grid sync.
// Advisory XCD-aware prefetch streams the apre slab for step t+2 into this
// XCD's L2 (coalesced float4), turning phase-B's scattered row gathers into
// L2 hits. Prefetch is purely a hint: no sync, no numeric effect.
__global__ __launch_bounds__(256) void k_sim(
    const float* __restrict__ Wg, const u64* __restrict__ prebits,
    const u64* __restrict__ prebitsT, const float* __restrict__ apre_all,
    float* __restrict__ out, unsigned* __restrict__ bar,
    float dmem, float dpost, float lrp, float lrm)
{
    int f = blockIdx.x;            // 0..1023
    int b = threadIdx.x;           // 0..255

    __shared__ float wv[NIN];      // w column f  (3.1 KB)
    __shared__ float apo[BB];      // apost column f (1 KB)
    __shared__ u64 smask[4];       // spk(t) bitmask over b
    __shared__ int shrk;           // per-XCD prefetch rank

    if (threadIdx.x == 0) {
        unsigned xcd;
        asm volatile("s_getreg_b32 %0, hwreg(HW_REG_XCC_ID)" : "=s"(xcd));
        shrk = (int)(at_add(bar + (xcd & 7u), 1u) & 127u);
    }
    for (int i = b; i < NIN; i += 256) wv[i] = Wg[f * NIN + i];  // W[f][i], coalesced
    float memv = 0.f, cntv = 0.f, apov = 0.f;
    u64 prev_bal = 0ull;           // this wave's spike ballot from t-1
    __syncthreads();
    const int rk = shrk;

    // advisory prefetch of slab tt into this XCD's L2 (128 chunks x 392 float4)
    auto prefetch = [&](int tt) {
        if (tt >= TSTEPS) return;
        const float4* src = (const float4*)(apre_all + (size_t)tt * (BB * NIN));
        int base = rk * 392;
        float acc = 0.f;
        for (int q = threadIdx.x; q < 392; q += 256) {
            float4 v = src[base + q];
            acc = acc + v.x + v.y + v.z + v.w;
        }
        asm volatile("" :: "v"(acc));   // keep loads live, no store
    };
    prefetch(0);
    prefetch(1);

    for (int t = 0; t < TSTEPS; ++t) {
        prefetch(t + 2);               // overlap with phase A + Sm compute

        // ===== phase A (thread = b) =====
        // apost = f32(f32(apost*decay) + spk_{t-1})   (own wave's prev ballot)
        apov = __fadd_rn(__fmul_rn(apov, dpost),
                         (float)((prev_bal >> (b & 63)) & 1ull));
        apo[b] = apov;

        // I = ((chunk0 + chunk1) + chunk2): sequential f32 folds, ascending i,
        // KC=384 chunks = words {0..5},{6..11},{12} — identical to round-4 order.
        const u64* pb = prebits + ((size_t)t * BB + b) * NW;
        u64 pw[NW];
        #pragma unroll
        for (int wd = 0; wd < NW; ++wd) pw[wd] = pb[wd];

        float I = 0.0f;
        {
            float c = 0.0f;
            #pragma unroll
            for (int wd = 0; wd < 6; ++wd) {
                u64 m = pw[wd]; int base = wd << 6;
                while (m) { int j = __builtin_ctzll(m); m &= m - 1;
                            c = __fadd_rn(c, wv[base + j]); }
            }
            I = __fadd_rn(I, c);
        }
        {
            float c = 0.0f;
            #pragma unroll
            for (int wd = 6; wd < 12; ++wd) {
                u64 m = pw[wd]; int base = wd << 6;
                while (m) { int j = __builtin_ctzll(m); m &= m - 1;
                            c = __fadd_rn(c, wv[base + j]); }
            }
            I = __fadd_rn(I, c);
        }
        {
            float c = 0.0f;
            u64 m = pw[12];
            while (m) { int j = __builtin_ctzll(m); m &= m - 1;
                        c = __fadd_rn(c, wv[768 + j]); }
            I = __fadd_rn(I, c);
        }

        float mm = __fadd_rn(__fmul_rn(memv, dmem), I);
        bool spk = (mm >= 16.0f);
        memv = spk ? 0.0f : mm;
        if (spk) cntv += 1.0f;
        u64 bal = __ballot(spk);
        prev_bal = bal;
        if ((b & 63) == 0) smask[b >> 6] = bal;
        __syncthreads();               // apo/smask visible to phase B

        // ===== phase B: w column update (skip at t=99, unused for output) =====
        if (t < TSTEPS - 1) {
            u64 s0 = smask[0], s1 = smask[1], s2 = smask[2], s3 = smask[3];
            const float* at = apre_all + (size_t)t * (BB * NIN);
            for (int i = b; i < NIN; i += 256) {
                // Sm = fold_{b' in pre(i)} apost[b',f], ascending b'
                const u64* pt = prebitsT + ((size_t)t * NIN + i) * 4;
                u64 q0 = pt[0], q1 = pt[1], q2 = pt[2], q3 = pt[3];
                float Sm = 0.0f;
                while (q0) { int j = __builtin_ctzll(q0); q0 &= q0 - 1; Sm = __fadd_rn(Sm, apo[j]); }
                while (q1) { int j = __builtin_ctzll(q1); q1 &= q1 - 1; Sm = __fadd_rn(Sm, apo[64 + j]); }
                while (q2) { int j = __builtin_ctzll(q2); q2 &= q2 - 1; Sm = __fadd_rn(Sm, apo[128 + j]); }
                while (q3) { int j = __builtin_ctzll(q3); q3 &= q3 - 1; Sm = __fadd_rn(Sm, apo[192 + j]); }
                // Sp = fold_{b' in spk(f)} apre[t][b'][i], ascending b' (coalesced in i)
                float Sp = 0.0f;
                u64 m;
                m = s0; while (m) { int j = __builtin_ctzll(m); m &= m - 1;
                                    Sp = __fadd_rn(Sp, at[(size_t)j * NIN + i]); }
                m = s1; while (m) { int j = __builtin_ctzll(m); m &= m - 1;
                                    Sp = __fadd_rn(Sp, at[(size_t)(64 + j) * NIN + i]); }
                m = s2; while (m) { int j = __builtin_ctzll(m); m &= m - 1;
                                    Sp = __fadd_rn(Sp, at[(size_t)(128 + j) * NIN + i]); }
                m = s3; while (m) { int j = __builtin_ctzll(m); m &= m - 1;
                                    Sp = __fadd_rn(Sp, at[(size_t)(192 + j) * NIN + i]); }

                float w = wv[i];
                w = __fadd_rn(w, __fmul_rn(lrp, Sp));
                w = __fsub_rn(w, __fmul_rn(lrm, Sm));
                w = fminf(fmaxf(w, 0.0f), 1.0f);
                wv[i] = w;                  // own element, no conflict
            }
        }
        __syncthreads();               // wv(t+1) visible to next phase A
    }

    out[b * FF + f] = cntv;            // spike counts, exact small ints
}

extern "C" void kernel_launch(void* const* d_in, const int* in_sizes, int n_in,
                              void* d_out, int out_size, void* d_ws, size_t ws_size,
                              hipStream_t stream)
{
    const float* image = (const float*)d_in[0];
    const float* W     = (const float*)d_in[1];
    const float* noise = (const float*)d_in[2];
    float* out = (float*)d_out;

    char* p = (char*)d_ws;
    u64* prebits   = (u64*)p;   p += (size_t)TSTEPS * BB * NW * 8;     // 2.66 MB
    u64* prebitsT  = (u64*)p;   p += (size_t)TSTEPS * NIN * 4 * 8;     // 2.51 MB
    float* apre_all = (float*)p; p += (size_t)TSTEPS * BB * NIN * 4;   // 80.3 MB
    unsigned* bar   = (unsigned*)p; p += 256;                          // rank counters

    float dmem = (float)exp(-1.0 / 20.0);   // np.float32(np.exp(-0.05))
    float dpre = dmem, dpost = dmem;
    float lrp = (float)(0.01 / 256.0);
    float lrm = (float)(0.012 / 256.0);

    k_encode<<<(TSTEPS * BB * NW * 64) / 256, 256, 0, stream>>>(image, noise, prebits);
    k_encode_t<<<(TSTEPS * NIN * BB) / 256, 256, 0, stream>>>(prebits, prebitsT);
    k_apre<<<(BB * NIN) / 256, 256, 0, stream>>>(prebits, apre_all, dpre, bar);
    k_sim<<<FF, 256, 0, stream>>>(W, prebits, prebitsT, apre_all, out, bar,
                                  dmem, dpost, lrp, lrm);
}

// Round 10
// 5928.481 us; speedup vs baseline: 1.6465x; 1.4131x over previous
//
#include <hip/hip_runtime.h>
#include <math.h>

#define TSTEPS 100
#define BB 256
#define FF 1024
#define NIN 784
#define NW 13           // 13*64 = 832 >= 784 bits per input row
#define CAPA 192        // max pre-spikes per (t,b)
#define CAPB 128        // max pre-spikes per (t,i)
#define NBLK 1024       // 4 blocks/CU x 256 CU, co-resident (VGPR-capped)
#define TPB 256

typedef unsigned long long u64;

// agent-scope atomics (coherence point; r8-proven for masks/counters)
__device__ __forceinline__ unsigned at_add(unsigned* p, unsigned v) {
    return __hip_atomic_fetch_add(p, v, __ATOMIC_RELAXED, __HIP_MEMORY_SCOPE_AGENT);
}
__device__ __forceinline__ unsigned at_ld(unsigned* p) {
    return __hip_atomic_load(p, __ATOMIC_RELAXED, __HIP_MEMORY_SCOPE_AGENT);
}
__device__ __forceinline__ void at_st(unsigned* p, unsigned v) {
    __hip_atomic_store(p, v, __ATOMIC_RELAXED, __HIP_MEMORY_SCOPE_AGENT);
}
__device__ __forceinline__ u64 at_ld64(u64* p) {
    return __hip_atomic_load(p, __ATOMIC_RELAXED, __HIP_MEMORY_SCOPE_AGENT);
}
__device__ __forceinline__ void at_st64(u64* p, u64 v) {
    __hip_atomic_store(p, v, __ATOMIC_RELAXED, __HIP_MEMORY_SCOPE_AGENT);
}

// L1-bypassing loads (stale-L1 dodge; values from XCD-local L2).
__device__ __forceinline__ float sc0_ld(const float* p) {
    float v;
    asm volatile("global_load_dword %0, %1, off sc0\n\t"
                 "s_waitcnt vmcnt(0)"
                 : "=v"(v) : "v"(p) : "memory");
    __builtin_amdgcn_sched_barrier(0);
    return v;
}
__device__ __forceinline__ void sc0_ld2(const float* p0, const float* p1,
                                        float& v0, float& v1) {
    asm volatile("global_load_dword %0, %2, off sc0\n\t"
                 "global_load_dword %1, %3, off sc0\n\t"
                 "s_waitcnt vmcnt(0)"
                 : "=&v"(v0), "=&v"(v1) : "v"(p0), "v"(p1) : "memory");
    __builtin_amdgcn_sched_barrier(0);
}
__device__ __forceinline__ void sc0_ld8(
    const float* p0, const float* p1, const float* p2, const float* p3,
    const float* p4, const float* p5, const float* p6, const float* p7,
    float& v0, float& v1, float& v2, float& v3,
    float& v4, float& v5, float& v6, float& v7)
{
    asm volatile(
        "global_load_dword %0, %8, off sc0\n\t"
        "global_load_dword %1, %9, off sc0\n\t"
        "global_load_dword %2, %10, off sc0\n\t"
        "global_load_dword %3, %11, off sc0\n\t"
        "global_load_dword %4, %12, off sc0\n\t"
        "global_load_dword %5, %13, off sc0\n\t"
        "global_load_dword %6, %14, off sc0\n\t"
        "global_load_dword %7, %15, off sc0\n\t"
        "s_waitcnt vmcnt(0)"
        : "=&v"(v0),"=&v"(v1),"=&v"(v2),"=&v"(v3),
          "=&v"(v4),"=&v"(v5),"=&v"(v6),"=&v"(v7)
        : "v"(p0),"v"(p1),"v"(p2),"v"(p3),"v"(p4),"v"(p5),"v"(p6),"v"(p7)
        : "memory");
    __builtin_amdgcn_sched_barrier(0);
}

// ---------- one-time init ----------
__global__ __launch_bounds__(256) void k_init(
    const float* __restrict__ W, float* __restrict__ wT,
    float* __restrict__ apreT_g, float* __restrict__ mem, float* __restrict__ apost,
    float* __restrict__ out, u64* __restrict__ spkbits, u64* __restrict__ spkT,
    unsigned* __restrict__ bar)
{
    int idx = blockIdx.x * 256 + threadIdx.x;          // covers NIN*FF = 802816
    {
        int f = idx & (FF - 1);
        int i = idx >> 10;
        wT[idx] = W[f * NIN + i];                      // wT[i][f] = W[f][i]
    }
    apreT_g[idx] = 0.f;                                // 8 copies = 2*802816 elems
    apreT_g[idx + NIN * FF] = 0.f;
    if (idx < BB * FF) { mem[idx] = 0.f; apost[idx] = 0.f; out[idx] = 0.f; }
    if (idx < BB * 16) spkbits[idx] = 0ull;
    if (idx < 2 * FF * 4) spkT[idx] = 0ull;
    if (idx < 4096) bar[idx] = 0u;
}

// ---------- Poisson encode (pure f32): p = image*0.2f; noise < p ----------
__global__ __launch_bounds__(256) void k_encode(
    const float* __restrict__ image, const float* __restrict__ noise,
    u64* __restrict__ prebits)
{
    int tid = blockIdx.x * 256 + threadIdx.x;
    int lane = threadIdx.x & 63;
    int word = tid >> 6;           // (t*BB + b)*NW + wd
    int wd = word % NW;
    int tb = word / NW;
    int b = tb & (BB - 1);
    int i = (wd << 6) + lane;
    bool s = false;
    if (i < NIN) {
        float pf = __fmul_rn(image[b * NIN + i], 0.2f);
        s = (noise[(size_t)tb * NIN + i] < pf);
    }
    u64 m = __ballot(s);
    if (lane == 0) prebits[word] = m;
}

// ---------- transposed prebits: prebitsT[t][i][wb] (bit = batch b) ----------
__global__ __launch_bounds__(256) void k_encode_t(
    const u64* __restrict__ prebits, u64* __restrict__ prebitsT)
{
    int tid = blockIdx.x * 256 + threadIdx.x;
    int b = tid & (BB - 1);
    int ti = tid >> 8;             // t*NIN + i
    int i = ti % NIN;
    int t = ti / NIN;
    u64 w = prebits[((size_t)t * BB + b) * NW + (i >> 6)];
    bool s = (w >> (i & 63)) & 1ull;
    u64 m = __ballot(s);
    if ((threadIdx.x & 63) == 0)
        prebitsT[(size_t)ti * 4 + ((threadIdx.x >> 6) & 3)] = m;
}

// ---------- index lists per (t,b): ascending i, KC=384 chunk marks ----------
__global__ __launch_bounds__(256) void k_lists(
    const u64* __restrict__ prebits, unsigned short* __restrict__ idxA,
    unsigned short* __restrict__ cntA)
{
    int tb = blockIdx.x * 256 + threadIdx.x;
    const u64* pb = prebits + (size_t)tb * NW;
    unsigned short* ia = idxA + (size_t)tb * CAPA;
    int n = 0, c1 = 0, c2 = 0;
    for (int wd = 0; wd < NW; ++wd) {
        u64 m = pb[wd];
        int boff = wd << 6;
        while (m) {
            int j = __builtin_ctzll(m); m &= m - 1;
            if (n < CAPA) ia[n] = (unsigned short)(boff + j);
            ++n;
        }
        if (wd == 5)  c1 = n;     // i < 384 boundary
        if (wd == 11) c2 = n;     // i < 768 boundary
    }
    if (n > CAPA) n = CAPA;
    if (c2 > n) c2 = n;
    if (c1 > c2) c1 = c2;
    cntA[tb * 4 + 0] = (unsigned short)c1;
    cntA[tb * 4 + 1] = (unsigned short)c2;
    cntA[tb * 4 + 2] = (unsigned short)n;
}

// ---------- b-lists per (t,i): ascending b ----------
__global__ __launch_bounds__(256) void k_listsT(
    const u64* __restrict__ prebitsT, unsigned char* __restrict__ idxB,
    unsigned short* __restrict__ cntB)
{
    int ti = blockIdx.x * 256 + threadIdx.x;
    if (ti >= TSTEPS * NIN) return;
    const u64* pt = prebitsT + (size_t)ti * 4;
    unsigned char* ib = idxB + (size_t)ti * CAPB;
    int n = 0;
    for (int wb = 0; wb < 4; ++wb) {
        u64 m = pt[wb];
        int boff = wb << 6;
        while (m) {
            int j = __builtin_ctzll(m); m &= m - 1;
            if (n < CAPB) ib[n] = (unsigned char)(boff + j);
            ++n;
        }
    }
    cntB[ti] = (unsigned short)(n > CAPB ? CAPB : n);
}

// ---------- persistent kernel: no cache maintenance, sc0 loads for cross-block ----------
__global__ __launch_bounds__(TPB, 4) void k_run(
    float* __restrict__ wT, float* __restrict__ apreT_g, float* __restrict__ apost,
    float* __restrict__ mem,
    const u64* __restrict__ prebits,
    const unsigned short* __restrict__ idxA, const unsigned short* __restrict__ cntA,
    const unsigned char* __restrict__ idxB, const unsigned short* __restrict__ cntB,
    u64* __restrict__ spkbits, u64* __restrict__ spkT,
    float* __restrict__ out, unsigned* __restrict__ bar,
    float dmem, float dpre, float dpost, float lrp, float lrm)
{
    __shared__ int sh[4];          // xcd, rank, nx, nsl
    __shared__ int shs[8];         // slice list for this XCD group
    __shared__ float sap[2][256];  // staged apreT row per sub
    const int tix = threadIdx.x;
    const int sub = tix >> 7, lane = tix & 127;

    if (tix == 0) {                // self-organize by actual XCD (r8-proven)
        unsigned xcd;
        asm volatile("s_getreg_b32 %0, hwreg(HW_REG_XCC_ID)" : "=s"(xcd));
        xcd &= 7u;
        unsigned rank = at_add(bar + xcd * 16, 1u);
        asm volatile("s_waitcnt vmcnt(0)" ::: "memory");
        unsigned a = at_add(bar + 128, 1u);
        if (a == NBLK - 1u) at_st(bar + 136, 1u);
        unsigned spins = 0;
        while (at_ld(bar + 136) == 0u) {
            if (++spins > (1u << 24)) break;
            __builtin_amdgcn_s_sleep(2);
        }
        int cnts[8]; int Kn = 0, gidx = 0;
        for (int x = 0; x < 8; ++x) cnts[x] = (int)at_ld(bar + x * 16);
        for (int x = 0; x < 8; ++x)
            if (cnts[x] > 0) { if (x == (int)xcd) gidx = Kn; ++Kn; }
        int ns = 0;
        for (int s = 0; s < 8; ++s) if ((s % Kn) == gidx) shs[ns++] = s;
        sh[0] = (int)xcd; sh[1] = (int)rank; sh[2] = cnts[xcd]; sh[3] = ns;
    }
    __syncthreads();
    const int xcd = sh[0], rank = sh[1], nx = sh[2], nsl = sh[3];
    float* apx = apreT_g + (size_t)xcd * (BB * NIN);   // [i*256 + b], XCD-local

    const int ukA = ((nsl << 8) + 2 * nx - 1) / (2 * nx);
    const int ukB = (nsl * NIN + 2 * nx - 1) / (2 * nx);
    unsigned ep = 1;

    for (int t = 0; t < TSTEPS; ++t) {
        u64* cur = spkT + (size_t)(t & 1) * (FF * 4);
        u64* nxt = spkT + (size_t)((t + 1) & 1) * (FF * 4);

        // ===== phase A: unit = (slice, b), 128 f-lanes, wave-uniform masks =====
        for (int q = 0; q < ukA; ++q) {
            int u = rank * 2 + sub + q * 2 * nx;
            if (u < (nsl << 8)) {
                int sl = u >> 8, b = u & 255;
                int f = (shs[sl] << 7) + lane;
                int tid = (b << 10) + f;

                // apost = f32(f32(apost*decay) + spk_{t-1})   (owner-stable, plain)
                u64 pw_ = spkbits[(b << 4) + (f >> 6)];
                float apo = __fadd_rn(__fmul_rn(apost[tid], dpost),
                                      (float)((pw_ >> (f & 63)) & 1ull));
                apost[tid] = apo;

                // I = ((chunk0+chunk1)+chunk2), list-order f32 folds, sc0 batched
                const unsigned short* ia = idxA + (size_t)(t * BB + b) * CAPA;
                const unsigned short* ca = cntA + (size_t)(t * BB + b) * 4;
                int c1 = ca[0], c2 = ca[1], c3 = ca[2];
                float I = 0.f;
                int k = 0;
                #pragma unroll 1
                for (int ch = 0; ch < 3; ++ch) {
                    int ke = (ch == 0) ? c1 : (ch == 1) ? c2 : c3;
                    float c = 0.f;
                    for (; k + 8 <= ke; k += 8) {
                        float v0,v1,v2,v3,v4,v5,v6,v7;
                        sc0_ld8(wT + ((int)ia[k+0] << 10) + f, wT + ((int)ia[k+1] << 10) + f,
                                wT + ((int)ia[k+2] << 10) + f, wT + ((int)ia[k+3] << 10) + f,
                                wT + ((int)ia[k+4] << 10) + f, wT + ((int)ia[k+5] << 10) + f,
                                wT + ((int)ia[k+6] << 10) + f, wT + ((int)ia[k+7] << 10) + f,
                                v0,v1,v2,v3,v4,v5,v6,v7);
                        c = __fadd_rn(c, v0); c = __fadd_rn(c, v1);
                        c = __fadd_rn(c, v2); c = __fadd_rn(c, v3);
                        c = __fadd_rn(c, v4); c = __fadd_rn(c, v5);
                        c = __fadd_rn(c, v6); c = __fadd_rn(c, v7);
                    }
                    for (; k < ke; ++k)
                        c = __fadd_rn(c, sc0_ld(wT + ((int)ia[k] << 10) + f));
                    I = __fadd_rn(I, c);
                }

                float mm = __fadd_rn(__fmul_rn(mem[tid], dmem), I);
                bool spk = (mm >= 16.0f);
                mem[tid] = spk ? 0.f : mm;
                if (spk) {
                    out[tid] += 1.f;
                    atomicOr(&cur[(f << 2) | (b >> 6)], 1ull << (b & 63));
                }
                u64 bal = __ballot(spk);
                if ((tix & 63) == 0) spkbits[(b << 4) + (f >> 6)] = bal;

                if (sl == 0) {   // owner of row b updates XCD-local transposed apre
                    const u64* pbr = prebits + ((size_t)t * BB + b) * NW;
                    for (int i2 = lane; i2 < NIN; i2 += 128) {
                        u64 w_ = pbr[i2 >> 6];
                        float pr = (float)((w_ >> (i2 & 63)) & 1ull);
                        int ai = (i2 << 8) + b;
                        apx[ai] = __fadd_rn(__fmul_rn(apx[ai], dpre), pr);
                    }
                }
            }
        }
        // zero next-parity spike masks (atomic domain)
        for (int wd = rank * TPB + tix; wd < (nsl << 9); wd += nx * TPB)
            at_st64(&nxt[(shs[wd >> 9] << 9) + (wd & 511)], 0ull);

        if (t == TSTEPS - 1) break;

        // ---- XCD-local barrier (no cache ops): 16-leaf arrival tree ----
        asm volatile("s_waitcnt vmcnt(0) lgkmcnt(0)" ::: "memory");
        __syncthreads();
        if (tix == 0) {
            int nsub = nx < 16 ? nx : 16;
            int sb = rank % nsub;
            unsigned need = (unsigned)((nx - sb + nsub - 1) / nsub);
            unsigned v = at_add(bar + 256 + (xcd * 16 + sb) * 16, 1u);
            if (v == need * ep - 1u) {
                unsigned r = at_add(bar + 2560 + xcd * 16, 1u);
                if (r == (unsigned)nsub * ep - 1u) at_st(bar + 2816 + xcd * 16, ep);
            }
            unsigned spins = 0;
            while (at_ld(bar + 2816 + xcd * 16) < ep) {
                if (++spins > (1u << 24)) break;
                __builtin_amdgcn_s_sleep(2);
            }
        }
        __syncthreads();
        ++ep;

        // ===== phase B: unit = (slice, i), 128 f-lanes =====
        for (int q = 0; q < ukB; ++q) {
            int u = rank * 2 + sub + q * 2 * nx;
            bool act = (u < nsl * NIN);
            int sl = act ? u / NIN : 0;
            int i = act ? (u - sl * NIN) : 0;
            int f = (shs[sl] << 7) + lane;
            float Sm = 0.f;
            u64 m0 = 0, m1 = 0, m2 = 0, m3 = 0;
            if (act) {
                // Sm = list-order fold over pre(i) of apost[b',f]  (sc0 batched)
                const unsigned char* ib = idxB + (size_t)(t * NIN + i) * CAPB;
                int cb = cntB[t * NIN + i];
                int k = 0;
                for (; k + 8 <= cb; k += 8) {
                    float v0,v1,v2,v3,v4,v5,v6,v7;
                    sc0_ld8(apost + ((int)ib[k+0] << 10) + f, apost + ((int)ib[k+1] << 10) + f,
                            apost + ((int)ib[k+2] << 10) + f, apost + ((int)ib[k+3] << 10) + f,
                            apost + ((int)ib[k+4] << 10) + f, apost + ((int)ib[k+5] << 10) + f,
                            apost + ((int)ib[k+6] << 10) + f, apost + ((int)ib[k+7] << 10) + f,
                            v0,v1,v2,v3,v4,v5,v6,v7);
                    Sm = __fadd_rn(Sm, v0); Sm = __fadd_rn(Sm, v1);
                    Sm = __fadd_rn(Sm, v2); Sm = __fadd_rn(Sm, v3);
                    Sm = __fadd_rn(Sm, v4); Sm = __fadd_rn(Sm, v5);
                    Sm = __fadd_rn(Sm, v6); Sm = __fadd_rn(Sm, v7);
                }
                for (; k < cb; ++k)
                    Sm = __fadd_rn(Sm, sc0_ld(apost + ((int)ib[k] << 10) + f));

                // stage apreT row i (coalesced sc0) into LDS for the mask walk
                float r0, r1;
                sc0_ld2(apx + (i << 8) + lane, apx + (i << 8) + 128 + lane, r0, r1);
                sap[sub][lane] = r0; sap[sub][128 + lane] = r1;

                m0 = at_ld64(&cur[(f << 2) | 0]);
                m1 = at_ld64(&cur[(f << 2) | 1]);
                m2 = at_ld64(&cur[(f << 2) | 2]);
                m3 = at_ld64(&cur[(f << 2) | 3]);
            }
            __syncthreads();
            if (act) {
                // Sp = ascending-b' fold over spk(f) of apre[b',i]  (LDS gather)
                const float* sp_ = sap[sub];
                float Sp = 0.f;
                u64 m;
                m = m0; while (m) { int j = __builtin_ctzll(m); m &= m - 1;
                                    Sp = __fadd_rn(Sp, sp_[j]); }
                m = m1; while (m) { int j = __builtin_ctzll(m); m &= m - 1;
                                    Sp = __fadd_rn(Sp, sp_[64 + j]); }
                m = m2; while (m) { int j = __builtin_ctzll(m); m &= m - 1;
                                    Sp = __fadd_rn(Sp, sp_[128 + j]); }
                m = m3; while (m) { int j = __builtin_ctzll(m); m &= m - 1;
                                    Sp = __fadd_rn(Sp, sp_[192 + j]); }

                int wi = (i << 10) + f;        // own row (rank-stable): plain
                float w = wT[wi];
                w = __fadd_rn(w, __fmul_rn(lrp, Sp));
                w = __fsub_rn(w, __fmul_rn(lrm, Sm));
                w = fminf(fmaxf(w, 0.f), 1.f);
                wT[wi] = w;
            }
            __syncthreads();
        }

        // ---- XCD-local barrier #2 ----
        asm volatile("s_waitcnt vmcnt(0) lgkmcnt(0)" ::: "memory");
        __syncthreads();
        if (tix == 0) {
            int nsub = nx < 16 ? nx : 16;
            int sb = rank % nsub;
            unsigned need = (unsigned)((nx - sb + nsub - 1) / nsub);
            unsigned v = at_add(bar + 256 + (xcd * 16 + sb) * 16, 1u);
            if (v == need * ep - 1u) {
                unsigned r = at_add(bar + 2560 + xcd * 16, 1u);
                if (r == (unsigned)nsub * ep - 1u) at_st(bar + 2816 + xcd * 16, ep);
            }
            unsigned spins = 0;
            while (at_ld(bar + 2816 + xcd * 16) < ep) {
                if (++spins > (1u << 24)) break;
                __builtin_amdgcn_s_sleep(2);
            }
        }
        __syncthreads();
        ++ep;
    }
}

extern "C" void kernel_launch(void* const* d_in, const int* in_sizes, int n_in,
                              void* d_out, int out_size, void* d_ws, size_t ws_size,
                              hipStream_t stream)
{
    const float* image = (const float*)d_in[0];
    const float* W     = (const float*)d_in[1];
    const float* noise = (const float*)d_in[2];
    float* out = (float*)d_out;

    char* p = (char*)d_ws;
    float* wT      = (float*)p; p += (size_t)NIN * FF * 4;              // 3.2 MB
    float* apreT_g = (float*)p; p += (size_t)8 * BB * NIN * 4;          // 6.4 MB (XCD copies)
    float* apost   = (float*)p; p += (size_t)BB * FF * 4;               // 1 MB
    float* mem     = (float*)p; p += (size_t)BB * FF * 4;               // 1 MB
    u64* prebits   = (u64*)p;   p += (size_t)TSTEPS * BB * NW * 8;      // 2.66 MB
    u64* prebitsT  = (u64*)p;   p += (size_t)TSTEPS * NIN * 4 * 8;      // 2.51 MB
    u64* spkbits   = (u64*)p;   p += (size_t)BB * 16 * 8;               // 32 KB
    u64* spkT      = (u64*)p;   p += (size_t)2 * FF * 4 * 8;            // 64 KB
    unsigned short* idxA = (unsigned short*)p; p += (size_t)TSTEPS * BB * CAPA * 2;
    unsigned short* cntA = (unsigned short*)p; p += (size_t)TSTEPS * BB * 4 * 2;
    unsigned char*  idxB = (unsigned char*)p;  p += (size_t)TSTEPS * NIN * CAPB;
    unsigned short* cntB = (unsigned short*)p; p += (size_t)TSTEPS * NIN * 2;
    unsigned* bar        = (unsigned*)p;       p += 4096 * 4;           // 16 KB

    float dmem = (float)exp(-1.0 / 20.0);   // np.float32(np.exp(-0.05))
    float dpre = dmem, dpost = dmem;
    float lrp = (float)(0.01 / 256.0);
    float lrm = (float)(0.012 / 256.0);

    k_init<<<(NIN * FF) / 256, 256, 0, stream>>>(
        W, wT, apreT_g, mem, apost, out, spkbits, spkT, bar);
    k_encode<<<(TSTEPS * BB * NW * 64) / 256, 256, 0, stream>>>(image, noise, prebits);
    k_encode_t<<<(TSTEPS * NIN * BB) / 256, 256, 0, stream>>>(prebits, prebitsT);
    k_lists<<<(TSTEPS * BB) / 256, 256, 0, stream>>>(prebits, idxA, cntA);
    k_listsT<<<(TSTEPS * NIN + 255) / 256, 256, 0, stream>>>(prebitsT, idxB, cntB);

    k_run<<<NBLK, TPB, 0, stream>>>(
        wT, apreT_g, apost, mem, prebits, idxA, cntA, idxB, cntB,
        spkbits, spkT, out, bar, dmem, dpre, dpost, lrp, lrm);
}

// Round 11
// 4842.164 us; speedup vs baseline: 2.0158x; 1.2243x over previous
//
#include <hip/hip_runtime.h>
#include <math.h>

#define TSTEPS 100
#define BB 256
#define FF 1024
#define NIN 784
#define NW 13           // 13*64 = 832 >= 784 bits per input row
#define CAPA 192        // max pre-spikes per (t,b)
#define CAPB 128        // max pre-spikes per (t,i)
#define NBLK 1024       // 4 blocks/CU
#define TPB 256         // 4 waves/block
#define BARSZ 17408     // u32: slots[1024] + arrive[8*1024] + release[8*1024]

typedef unsigned long long u64;
typedef float f4 __attribute__((ext_vector_type(4)));

// agent-scope atomics (coherence point; r8/r10-proven)
__device__ __forceinline__ unsigned at_ld(unsigned* p) {
    return __hip_atomic_load(p, __ATOMIC_RELAXED, __HIP_MEMORY_SCOPE_AGENT);
}
__device__ __forceinline__ void at_st(unsigned* p, unsigned v) {
    __hip_atomic_store(p, v, __ATOMIC_RELAXED, __HIP_MEMORY_SCOPE_AGENT);
}
__device__ __forceinline__ u64 at_ld64(u64* p) {
    return __hip_atomic_load(p, __ATOMIC_RELAXED, __HIP_MEMORY_SCOPE_AGENT);
}
__device__ __forceinline__ void at_st64(u64* p, u64 v) {
    __hip_atomic_store(p, v, __ATOMIC_RELAXED, __HIP_MEMORY_SCOPE_AGENT);
}

// L1-bypassing loads (r10-proven syntax; values come from XCD-local L2)
__device__ __forceinline__ float sc0_ld(const float* p) {
    float v;
    asm volatile("global_load_dword %0, %1, off sc0\n\t"
                 "s_waitcnt vmcnt(0)"
                 : "=v"(v) : "v"(p) : "memory");
    __builtin_amdgcn_sched_barrier(0);
    return v;
}
__device__ __forceinline__ f4 sc0_ld4(const f4* p) {
    f4 v;
    asm volatile("global_load_dwordx4 %0, %1, off sc0\n\t"
                 "s_waitcnt vmcnt(0)"
                 : "=v"(v) : "v"(p) : "memory");
    __builtin_amdgcn_sched_barrier(0);
    return v;
}
__device__ __forceinline__ void sc0_issue8(
    const float* p0, const float* p1, const float* p2, const float* p3,
    const float* p4, const float* p5, const float* p6, const float* p7,
    float& v0, float& v1, float& v2, float& v3,
    float& v4, float& v5, float& v6, float& v7)
{
    asm volatile(
        "global_load_dword %0, %8, off sc0\n\t"
        "global_load_dword %1, %9, off sc0\n\t"
        "global_load_dword %2, %10, off sc0\n\t"
        "global_load_dword %3, %11, off sc0\n\t"
        "global_load_dword %4, %12, off sc0\n\t"
        "global_load_dword %5, %13, off sc0\n\t"
        "global_load_dword %6, %14, off sc0\n\t"
        "global_load_dword %7, %15, off sc0"
        : "=&v"(v0),"=&v"(v1),"=&v"(v2),"=&v"(v3),
          "=&v"(v4),"=&v"(v5),"=&v"(v6),"=&v"(v7)
        : "v"(p0),"v"(p1),"v"(p2),"v"(p3),"v"(p4),"v"(p5),"v"(p6),"v"(p7)
        : "memory");
}
__device__ __forceinline__ void sc0_ld8(
    const float* p0, const float* p1, const float* p2, const float* p3,
    const float* p4, const float* p5, const float* p6, const float* p7,
    float& v0, float& v1, float& v2, float& v3,
    float& v4, float& v5, float& v6, float& v7)
{
    sc0_issue8(p0,p1,p2,p3,p4,p5,p6,p7, v0,v1,v2,v3,v4,v5,v6,v7);
    asm volatile("s_waitcnt vmcnt(0)" ::: "memory");
    __builtin_amdgcn_sched_barrier(0);
}

// sequential f32 fold over base[list[k]<<10 + f], ascending k — list order
// is the VERIFIED numpy fold order; batching changes only load timing.
template <typename IDX>
__device__ __forceinline__ float foldList(
    const float* __restrict__ base, const IDX* __restrict__ list,
    int k0, int k1, int f)
{
    float c = 0.f;
    int k = k0;
    for (; k + 16 <= k1; k += 16) {
        float v0,v1,v2,v3,v4,v5,v6,v7,v8,v9,v10,v11,v12,v13,v14,v15;
        sc0_issue8(base+((int)list[k+0]<<10)+f, base+((int)list[k+1]<<10)+f,
                   base+((int)list[k+2]<<10)+f, base+((int)list[k+3]<<10)+f,
                   base+((int)list[k+4]<<10)+f, base+((int)list[k+5]<<10)+f,
                   base+((int)list[k+6]<<10)+f, base+((int)list[k+7]<<10)+f,
                   v0,v1,v2,v3,v4,v5,v6,v7);
        sc0_issue8(base+((int)list[k+8]<<10)+f,  base+((int)list[k+9]<<10)+f,
                   base+((int)list[k+10]<<10)+f, base+((int)list[k+11]<<10)+f,
                   base+((int)list[k+12]<<10)+f, base+((int)list[k+13]<<10)+f,
                   base+((int)list[k+14]<<10)+f, base+((int)list[k+15]<<10)+f,
                   v8,v9,v10,v11,v12,v13,v14,v15);
        asm volatile("s_waitcnt vmcnt(0)" ::: "memory");
        __builtin_amdgcn_sched_barrier(0);
        c=__fadd_rn(c,v0);  c=__fadd_rn(c,v1);  c=__fadd_rn(c,v2);  c=__fadd_rn(c,v3);
        c=__fadd_rn(c,v4);  c=__fadd_rn(c,v5);  c=__fadd_rn(c,v6);  c=__fadd_rn(c,v7);
        c=__fadd_rn(c,v8);  c=__fadd_rn(c,v9);  c=__fadd_rn(c,v10); c=__fadd_rn(c,v11);
        c=__fadd_rn(c,v12); c=__fadd_rn(c,v13); c=__fadd_rn(c,v14); c=__fadd_rn(c,v15);
    }
    if (k + 8 <= k1) {
        float v0,v1,v2,v3,v4,v5,v6,v7;
        sc0_ld8(base+((int)list[k+0]<<10)+f, base+((int)list[k+1]<<10)+f,
                base+((int)list[k+2]<<10)+f, base+((int)list[k+3]<<10)+f,
                base+((int)list[k+4]<<10)+f, base+((int)list[k+5]<<10)+f,
                base+((int)list[k+6]<<10)+f, base+((int)list[k+7]<<10)+f,
                v0,v1,v2,v3,v4,v5,v6,v7);
        c=__fadd_rn(c,v0); c=__fadd_rn(c,v1); c=__fadd_rn(c,v2); c=__fadd_rn(c,v3);
        c=__fadd_rn(c,v4); c=__fadd_rn(c,v5); c=__fadd_rn(c,v6); c=__fadd_rn(c,v7);
        k += 8;
    }
    for (; k < k1; ++k)
        c = __fadd_rn(c, sc0_ld(base + ((int)list[k] << 10) + f));
    return c;
}

// ---------- one-time init ----------
__global__ __launch_bounds__(256) void k_init(
    const float* __restrict__ W, float* __restrict__ wT,
    float* __restrict__ apreT_g, u64* __restrict__ spkT,
    unsigned* __restrict__ bar)
{
    int idx = blockIdx.x * 256 + threadIdx.x;          // covers NIN*FF = 802816
    {
        int f = idx & (FF - 1);
        int i = idx >> 10;
        wT[idx] = W[f * NIN + i];                      // wT[i][f] = W[f][i]
    }
    apreT_g[idx] = 0.f;                                // 8 XCD copies
    apreT_g[idx + NIN * FF] = 0.f;
    if (idx < 2 * FF * 4) spkT[idx] = 0ull;
    if (idx < BARSZ) bar[idx] = 0u;                    // replay-safe reset
}

// ---------- Poisson encode (pure f32): p = image*0.2f; noise < p ----------
__global__ __launch_bounds__(256) void k_encode(
    const float* __restrict__ image, const float* __restrict__ noise,
    u64* __restrict__ prebits)
{
    int tid = blockIdx.x * 256 + threadIdx.x;
    int lane = threadIdx.x & 63;
    int word = tid >> 6;           // (t*BB + b)*NW + wd
    int wd = word % NW;
    int tb = word / NW;
    int b = tb & (BB - 1);
    int i = (wd << 6) + lane;
    bool s = false;
    if (i < NIN) {
        float pf = __fmul_rn(image[b * NIN + i], 0.2f);
        s = (noise[(size_t)tb * NIN + i] < pf);
    }
    u64 m = __ballot(s);
    if (lane == 0) prebits[word] = m;
}

// ---------- transposed prebits: prebitsT[t][i][wb] (bit = batch b) ----------
__global__ __launch_bounds__(256) void k_encode_t(
    const u64* __restrict__ prebits, u64* __restrict__ prebitsT)
{
    int tid = blockIdx.x * 256 + threadIdx.x;
    int b = tid & (BB - 1);
    int ti = tid >> 8;             // t*NIN + i
    int i = ti % NIN;
    int t = ti / NIN;
    u64 w = prebits[((size_t)t * BB + b) * NW + (i >> 6)];
    bool s = (w >> (i & 63)) & 1ull;
    u64 m = __ballot(s);
    if ((threadIdx.x & 63) == 0)
        prebitsT[(size_t)ti * 4 + ((threadIdx.x >> 6) & 3)] = m;
}

// ---------- index lists per (t,b): ascending i, KC=384 chunk marks ----------
__global__ __launch_bounds__(256) void k_lists(
    const u64* __restrict__ prebits, unsigned short* __restrict__ idxA,
    unsigned short* __restrict__ cntA)
{
    int tb = blockIdx.x * 256 + threadIdx.x;
    const u64* pb = prebits + (size_t)tb * NW;
    unsigned short* ia = idxA + (size_t)tb * CAPA;
    int n = 0, c1 = 0, c2 = 0;
    for (int wd = 0; wd < NW; ++wd) {
        u64 m = pb[wd];
        int boff = wd << 6;
        while (m) {
            int j = __builtin_ctzll(m); m &= m - 1;
            if (n < CAPA) ia[n] = (unsigned short)(boff + j);
            ++n;
        }
        if (wd == 5)  c1 = n;     // i < 384 boundary
        if (wd == 11) c2 = n;     // i < 768 boundary
    }
    if (n > CAPA) n = CAPA;
    if (c2 > n) c2 = n;
    if (c1 > c2) c1 = c2;
    cntA[tb * 4 + 0] = (unsigned short)c1;
    cntA[tb * 4 + 1] = (unsigned short)c2;
    cntA[tb * 4 + 2] = (unsigned short)n;
}

// ---------- b-lists per (t,i): ascending b ----------
__global__ __launch_bounds__(256) void k_listsT(
    const u64* __restrict__ prebitsT, unsigned char* __restrict__ idxB,
    unsigned short* __restrict__ cntB)
{
    int ti = blockIdx.x * 256 + threadIdx.x;
    if (ti >= TSTEPS * NIN) return;
    const u64* pt = prebitsT + (size_t)ti * 4;
    unsigned char* ib = idxB + (size_t)ti * CAPB;
    int n = 0;
    for (int wb = 0; wb < 4; ++wb) {
        u64 m = pt[wb];
        int boff = wb << 6;
        while (m) {
            int j = __builtin_ctzll(m); m &= m - 1;
            if (n < CAPB) ib[n] = (unsigned char)(boff + j);
            ++n;
        }
    }
    cntB[ti] = (unsigned short)(n > CAPB ? CAPB : n);
}

// ---------- persistent kernel: wave-granular units, store/poll barrier ----------
__global__ __launch_bounds__(TPB, 4) void k_run(
    float* __restrict__ wT, float* __restrict__ apreT_g, float* __restrict__ apost,
    const unsigned short* __restrict__ idxA, const unsigned short* __restrict__ cntA,
    const unsigned char* __restrict__ idxB, const unsigned short* __restrict__ cntB,
    const u64* __restrict__ prebitsT, u64* __restrict__ spkT,
    float* __restrict__ out, unsigned* __restrict__ bar,
    float dmem, float dpre, float dpost, float lrp, float lrm)
{
    __shared__ int shs[16];          // slice list for this XCD group
    __shared__ int shinfo[4];        // xcd, rank, nx, nsl
    __shared__ unsigned scnt[9];     // 8 per-XCD counts + my rank
    __shared__ int sbad;
    __shared__ float sap[4][256];    // per-wave Sp staging

    const int tix = threadIdx.x;
    const int wv = tix >> 6, lane = tix & 63;
    const int bid = blockIdx.x;

    // ===== RMW-free self-organization =====
    unsigned* slot = bar;                       // [1024]
    if (tix < 9) scnt[tix] = 0u;
    if (tix == 0) {
        unsigned x;
        asm volatile("s_getreg_b32 %0, hwreg(HW_REG_XCC_ID)" : "=s"(x));
        shinfo[0] = (int)(x & 7u);
        at_st(&slot[bid], (x & 7u) + 1u);
    }
    __syncthreads();
    const int xcd = shinfo[0];
    unsigned mv0, mv1, mv2, mv3;
    for (int rounds = 0;; ++rounds) {
        if (tix == 0) sbad = 0;
        __syncthreads();
        mv0 = at_ld(&slot[tix]);
        mv1 = at_ld(&slot[256 + tix]);
        mv2 = at_ld(&slot[512 + tix]);
        mv3 = at_ld(&slot[768 + tix]);
        if (!(mv0 && mv1 && mv2 && mv3)) sbad = 1;
        __syncthreads();
        if (!sbad || rounds > (1 << 20)) break;
        __builtin_amdgcn_s_sleep(2);
    }
    {   // counts + my rank from the (complete) slot snapshot
        atomicAdd(&scnt[mv0 - 1u], 1u);
        atomicAdd(&scnt[mv1 - 1u], 1u);
        atomicAdd(&scnt[mv2 - 1u], 1u);
        atomicAdd(&scnt[mv3 - 1u], 1u);
        unsigned r = 0;
        if ((int)(mv0 - 1u) == xcd && tix < bid) r++;
        if ((int)(mv1 - 1u) == xcd && 256 + tix < bid) r++;
        if ((int)(mv2 - 1u) == xcd && 512 + tix < bid) r++;
        if ((int)(mv3 - 1u) == xcd && 768 + tix < bid) r++;
        if (r) atomicAdd(&scnt[8], r);
        __syncthreads();
        if (tix == 0) {
            int Kn = 0, gidx = 0;
            for (int x2 = 0; x2 < 8; ++x2)
                if (scnt[x2] > 0) { if (x2 == xcd) gidx = Kn; ++Kn; }
            int ns = 0;
            for (int s = 0; s < 16; ++s)
                if ((s % Kn) == gidx) shs[ns++] = s;
            shinfo[1] = (int)scnt[8];
            shinfo[2] = (int)scnt[xcd];
            shinfo[3] = ns;
        }
        __syncthreads();
    }
    const int rank = shinfo[1], nx = shinfo[2], nsl = shinfo[3];
    const int nxw = nx * 4;
    const int wrank = rank * 4 + wv;
    const int nA = nsl << 8;          // (slice, b) units
    const int nB = nsl * NIN;         // (slice, i) units
    float* apx = apreT_g + (size_t)xcd * (BB * NIN);   // [i*256+b], XCD-local
    float* sapw = sap[wv];
    unsigned* arrive  = bar + 1024 + xcd * 1024;
    unsigned* release = bar + 9216 + xcd * 1024;
    unsigned ep = 1;

    // register-resident per-unit state (owner wave fixed for the whole run)
#define A_STATE(Q) float memv##Q = 0.f, cntv##Q = 0.f, apov##Q = 0.f; u64 pbal##Q = 0ull;
    A_STATE(0) A_STATE(1) A_STATE(2) A_STATE(3)

#define DO_A(Q) do { \
    int u = wrank + (Q) * nxw; \
    if (u < nA) { \
        int sl = u >> 8, b = u & 255; \
        int f = (shs[sl] << 6) + lane; \
        apov##Q = __fadd_rn(__fmul_rn(apov##Q, dpost), \
                            (float)((pbal##Q >> lane) & 1ull)); \
        apost[(b << 10) + f] = apov##Q; \
        const unsigned short* ia = idxA + (size_t)(t * BB + b) * CAPA; \
        const unsigned short* ca = cntA + (size_t)(t * BB + b) * 4; \
        int c1 = ca[0], c2 = ca[1], c3 = ca[2]; \
        float I = 0.f; \
        I = __fadd_rn(I, foldList(wT, ia, 0,  c1, f)); \
        I = __fadd_rn(I, foldList(wT, ia, c1, c2, f)); \
        I = __fadd_rn(I, foldList(wT, ia, c2, c3, f)); \
        float mm = __fadd_rn(__fmul_rn(memv##Q, dmem), I); \
        bool spk = (mm >= 16.0f); \
        memv##Q = spk ? 0.f : mm; \
        if (spk) { \
            cntv##Q += 1.f; \
            atomicOr(&cur[(f << 2) | (b >> 6)], 1ull << (b & 63)); \
        } \
        pbal##Q = __ballot(spk); \
    } \
} while (0)

    // store/poll barrier: no RMW anywhere; leader (rank 0) vector-polls
    auto xbar = [&]() {
        asm volatile("s_waitcnt vmcnt(0) lgkmcnt(0)" ::: "memory");
        __syncthreads();
        if (rank == 0) {
            for (int rounds = 0;; ++rounds) {
                if (tix == 0) sbad = 0;
                __syncthreads();
                bool ok = true;
                #pragma unroll
                for (int kk = 0; kk < 4; ++kk) {
                    int r = kk * 256 + tix;
                    if (r < nx && r > 0) ok &= (at_ld(&arrive[r]) >= ep);
                }
                if (!ok) sbad = 1;
                __syncthreads();
                if (!sbad || rounds > (1 << 20)) break;
                __builtin_amdgcn_s_sleep(4);
            }
            #pragma unroll
            for (int kk = 0; kk < 4; ++kk) {
                int r = kk * 256 + tix;
                if (r < nx) at_st(&release[r], ep);
            }
        } else {
            if (tix == 0) {
                at_st(&arrive[rank], ep);
                unsigned spins = 0;
                while (at_ld(&release[rank]) < ep) {
                    if (++spins > (1u << 22)) break;
                    __builtin_amdgcn_s_sleep(8);
                }
            }
            __syncthreads();
        }
        ++ep;
    };

    for (int t = 0; t < TSTEPS; ++t) {
        u64* cur = spkT + (size_t)(t & 1) * (FF * 4);
        u64* nxt = spkT + (size_t)((t + 1) & 1) * (FF * 4);

        // ===== phase A (wave-local; no intra-block sync) =====
        DO_A(0); DO_A(1); DO_A(2); DO_A(3);

        // apre update: coalesced float4 RMW per row (owner-stable; readers sc0)
        for (int r = wrank; r < NIN; r += nxw) {
            const u64* pt = prebitsT + ((size_t)t * NIN + r) * 4;
            u64 w0 = pt[0], w1 = pt[1], w2 = pt[2], w3 = pt[3];
            int bb = lane << 2;
            u64 wsel = (bb & 128) ? ((bb & 64) ? w3 : w2)
                                  : ((bb & 64) ? w1 : w0);
            int s0 = bb & 63;
            f4* vp = (f4*)(apx + ((size_t)r << 8) + bb);
            f4 v = *vp;
            v.x = __fadd_rn(__fmul_rn(v.x, dpre), (float)((wsel >> s0) & 1ull));
            v.y = __fadd_rn(__fmul_rn(v.y, dpre), (float)((wsel >> (s0+1)) & 1ull));
            v.z = __fadd_rn(__fmul_rn(v.z, dpre), (float)((wsel >> (s0+2)) & 1ull));
            v.w = __fadd_rn(__fmul_rn(v.w, dpre), (float)((wsel >> (s0+3)) & 1ull));
            *vp = v;
        }
        // zero next-parity spike masks for my slices
        for (int wd0 = rank * TPB + tix; wd0 < (nsl << 8); wd0 += nx * TPB) {
            int sl = wd0 >> 8, rest = wd0 & 255;
            int f = (shs[sl] << 6) + (rest >> 2);
            at_st64(&nxt[(f << 2) + (rest & 3)], 0ull);
        }

        if (t == TSTEPS - 1) break;
        xbar();

        // ===== phase B (wave-local units) =====
        for (int q = 0;; ++q) {
            int u = wrank + q * nxw;
            if (u >= nB) break;
            int sl = u / NIN, i = u - sl * NIN;
            int f = (shs[sl] << 6) + lane;

            // Sm: list-order fold over pre(i) of apost[b',f]
            const unsigned char* ib = idxB + (size_t)(t * NIN + i) * CAPB;
            int cb = cntB[t * NIN + i];
            float Sm = foldList(apost, ib, 0, cb, f);

            // stage apre row i into this wave's LDS buffer (sc0, coalesced)
            asm volatile("s_waitcnt lgkmcnt(0)" ::: "memory");
            __builtin_amdgcn_sched_barrier(0);
            f4 rv = sc0_ld4((const f4*)(apx + ((size_t)i << 8) + (lane << 2)));
            *(f4*)(sapw + (lane << 2)) = rv;
            u64 m0 = at_ld64(&cur[(f << 2) | 0]);
            u64 m1 = at_ld64(&cur[(f << 2) | 1]);
            u64 m2 = at_ld64(&cur[(f << 2) | 2]);
            u64 m3 = at_ld64(&cur[(f << 2) | 3]);
            asm volatile("s_waitcnt lgkmcnt(0)" ::: "memory");
            __builtin_amdgcn_sched_barrier(0);

            // Sp: ascending-b fold over spk(f) of apre[b',i] (LDS gather)
            float Sp = 0.f;
            u64 m;
            m = m0; while (m) { int j = __builtin_ctzll(m); m &= m - 1;
                                Sp = __fadd_rn(Sp, sapw[j]); }
            m = m1; while (m) { int j = __builtin_ctzll(m); m &= m - 1;
                                Sp = __fadd_rn(Sp, sapw[64 + j]); }
            m = m2; while (m) { int j = __builtin_ctzll(m); m &= m - 1;
                                Sp = __fadd_rn(Sp, sapw[128 + j]); }
            m = m3; while (m) { int j = __builtin_ctzll(m); m &= m - 1;
                                Sp = __fadd_rn(Sp, sapw[192 + j]); }

            int wi = (i << 10) + f;            // owner-stable row: plain RMW
            float w = wT[wi];
            w = __fadd_rn(w, __fmul_rn(lrp, Sp));
            w = __fsub_rn(w, __fmul_rn(lrm, Sm));
            w = fminf(fmaxf(w, 0.f), 1.f);
            wT[wi] = w;
        }
        xbar();
    }

    // spike counts from registers (every (b,f) covered exactly once)
#define DO_OUT(Q) do { \
    int u = wrank + (Q) * nxw; \
    if (u < nA) { \
        int sl = u >> 8, b = u & 255; \
        int f = (shs[sl] << 6) + lane; \
        out[(b << 10) + f] = cntv##Q; \
    } \
} while (0)
    DO_OUT(0); DO_OUT(1); DO_OUT(2); DO_OUT(3);
}

extern "C" void kernel_launch(void* const* d_in, const int* in_sizes, int n_in,
                              void* d_out, int out_size, void* d_ws, size_t ws_size,
                              hipStream_t stream)
{
    const float* image = (const float*)d_in[0];
    const float* W     = (const float*)d_in[1];
    const float* noise = (const float*)d_in[2];
    float* out = (float*)d_out;

    char* p = (char*)d_ws;
    float* wT      = (float*)p; p += (size_t)NIN * FF * 4;              // 3.2 MB
    float* apreT_g = (float*)p; p += (size_t)8 * BB * NIN * 4;          // 6.4 MB
    float* apost   = (float*)p; p += (size_t)BB * FF * 4;               // 1 MB
    u64* prebits   = (u64*)p;   p += (size_t)TSTEPS * BB * NW * 8;      // 2.66 MB
    u64* prebitsT  = (u64*)p;   p += (size_t)TSTEPS * NIN * 4 * 8;      // 2.51 MB
    u64* spkT      = (u64*)p;   p += (size_t)2 * FF * 4 * 8;            // 64 KB
    unsigned short* idxA = (unsigned short*)p; p += (size_t)TSTEPS * BB * CAPA * 2;
    unsigned short* cntA = (unsigned short*)p; p += (size_t)TSTEPS * BB * 4 * 2;
    unsigned char*  idxB = (unsigned char*)p;  p += (size_t)TSTEPS * NIN * CAPB;
    unsigned short* cntB = (unsigned short*)p; p += (size_t)TSTEPS * NIN * 2;
    unsigned* bar        = (unsigned*)p;       p += (size_t)BARSZ * 4;  // 68 KB

    float dmem = (float)exp(-1.0 / 20.0);   // np.float32(np.exp(-0.05))
    float dpre = dmem, dpost = dmem;
    float lrp = (float)(0.01 / 256.0);
    float lrm = (float)(0.012 / 256.0);

    k_init<<<(NIN * FF) / 256, 256, 0, stream>>>(W, wT, apreT_g, spkT, bar);
    k_encode<<<(TSTEPS * BB * NW * 64) / 256, 256, 0, stream>>>(image, noise, prebits);
    k_encode_t<<<(TSTEPS * NIN * BB) / 256, 256, 0, stream>>>(prebits, prebitsT);
    k_lists<<<(TSTEPS * BB) / 256, 256, 0, stream>>>(prebits, idxA, cntA);
    k_listsT<<<(TSTEPS * NIN + 255) / 256, 256, 0, stream>>>(prebitsT, idxB, cntB);

    k_run<<<NBLK, TPB, 0, stream>>>(
        wT, apreT_g, apost, idxA, cntA, idxB, cntB,
        prebitsT, spkT, out, bar, dmem, dpre, dpost, lrp, lrm);
}